// Round 8
// baseline (129.836 us; speedup 1.0000x reference)
//
#include <hip/hip_runtime.h>

#define NTOK 32
#define PADT 1
#define MLEN 512
#define NLEN 1024
#define EPS_F 1e-7f

// LDS float offsets. tok+wtmp sit BEFORE nl and serve as the front guard for
// negative stream indices (down to -63 floats); tail guard covers prefetch
// overrun (up to +67 floats past nl end).
#define OFF_TOK 0                         // tok[512] int
#define OFF_WT  512                       // wtmp[16]
#define OFF_NL  528                       // nl[32][1024] fp32 = -log(clip(p)) [token][frame]
#define OFF_TAIL (OFF_NL + NTOK*NLEN)     // 33296
#define LDS_FLOATS (OFF_TAIL + 160)       // 33456 floats = 133,824 B

__device__ __forceinline__ float min3f(float a, float b, float c) {
  return fminf(fminf(a, b), c);   // AMDGPU backend folds to v_min3_f32
}
// result[lane l] = src[l-1] for l>=1; old[l] for lane 0 (wave_shr:1, bound_ctrl=false)
__device__ __forceinline__ float dpp_shr1(float old_v, float src) {
  return __int_as_float(__builtin_amdgcn_update_dpp(
      __float_as_int(old_v), __float_as_int(src), 0x138, 0xF, 0xF, false));
}

// One iteration = 4 column-slots. Lane l owns rows 8l+1..8l+8; at slot s it
// computes col jj = s - l + 1 for all 8 rows. z[r] = D[8l+r+1][jj-1] entering
// the slot. ztop = D[8l][jj-1] (diag for r=0). up (dpp of z[7]) = D[8l][jj].
// run = row-0 prefix (only lane 0's value is consumed, via dpp old).
// All stream loads issued here are consumed NEXT call (ping-pong C/N).
template <bool MASKED>
__device__ __forceinline__ void dp_iter4(
    const float* (&P)[9],
    float (&C)[9][4], float (&N)[9][4],
    float& ztop, float (&z)[8], float& run,
    int& s, const int lane)
{
  // prefetch next 4 slots of all 9 streams (8 sub rows + ins)
#pragma unroll
  for (int r = 0; r < 9; ++r) {
#pragma unroll
    for (int c = 0; c < 4; ++c) N[r][c] = P[r][4 + c];
    P[r] += 4;
  }
#pragma unroll
  for (int j = 0; j < 4; ++j) {
    float insv = C[8][j];
    float runn = run + insv;                 // D[0][jj] for this lane's jj
    float up = dpp_shr1(runn, z[7]);         // D[8l][jj] (lane-1 bottom row / row-0 boundary)
    float nm[8];
    nm[0] = min3f(ztop + C[0][j], z[0] + insv, up + 1.0f);
#pragma unroll
    for (int r = 1; r < 8; ++r)
      nm[r] = min3f(z[r-1] + C[r][j], z[r] + insv, nm[r-1] + 1.0f);
    if (MASKED) {
      bool act = ((unsigned)(s + j - lane)) < 1024u;
      run  = act ? runn : run;
      ztop = act ? up : ztop;
#pragma unroll
      for (int r = 0; r < 8; ++r) z[r] = act ? nm[r] : z[r];
    } else {
      run = runn; ztop = up;
#pragma unroll
      for (int r = 0; r < 8; ++r) z[r] = nm[r];
    }
  }
  s += 4;
}

__global__ __launch_bounds__(256, 1) void align_loss_kernel(
    const int* __restrict__ y_true, const float* __restrict__ y_pred,
    float* __restrict__ partial)
{
  extern __shared__ float smem[];
  int*   tok  = (int*)(smem + OFF_TOK);
  float* wtmp = smem + OFF_WT;
  int*   wti  = (int*)wtmp;
  float* nl   = smem + OFF_NL;

  const int b = blockIdx.x;
  const int t = threadIdx.x;
  const int lane = t & 63;
  const int wv = t >> 6;

  // ---- zero token buffer ----
  tok[t] = 0; tok[t + 256] = 0;
  __syncthreads();

  // ---- Phase A: left-shift compaction (2 halves of 256) ----
  int total = 0;
  for (int h = 0; h < 2; ++h) {
    int yt = y_true[b * MLEN + h * 256 + t];
    bool f = (yt != PADT);
    unsigned long long m = __ballot(f);
    int wp = __popcll(m & ((1ull << lane) - 1ull));
    if (lane == 0) wti[8 + wv] = __popcll(m);
    __syncthreads();
    int offs = total, ht = 0;
#pragma unroll
    for (int w2 = 0; w2 < 4; ++w2) { int cnt = wti[8 + w2]; if (w2 < wv) offs += cnt; ht += cnt; }
    if (f) tok[offs + wp] = yt;
    total += ht;
    __syncthreads();
  }
  const int L = total;

  // ---- Phase B: nl[tk][r] = -log(clip(y_pred[b,r,tk]/sum)), fp32 ----
  for (int r = t; r < NLEN; r += 256) {
    const float4* rp = (const float4*)(y_pred + ((size_t)b * NLEN + r) * NTOK);
    float4 q[8]; float sm = 0.f;
#pragma unroll
    for (int u = 0; u < 8; ++u) { q[u] = rp[u]; sm += q[u].x + q[u].y + q[u].z + q[u].w; }
    float inv = 1.0f / sm;
#pragma unroll
    for (int u = 0; u < 8; ++u) {
      float pv[4] = {q[u].x, q[u].y, q[u].z, q[u].w};
#pragma unroll
      for (int c2 = 0; c2 < 4; ++c2) {
        float p = pv[c2] * inv;
        p = fminf(fmaxf(p, EPS_F), 1.0f - EPS_F);
        nl[(u * 4 + c2) * NLEN + r] = -__logf(p);
      }
    }
  }
  __syncthreads();

  // ---- DP: wave 0 only, all 512 rows, single systolic sweep ----
  if (wv == 0) {
    const int base_row = 8 * lane;
    int tk[8];
#pragma unroll
    for (int r = 0; r < 8; ++r) tk[r] = tok[base_row + r];

    const float* P[9];
#pragma unroll
    for (int r = 0; r < 8; ++r) P[r] = nl + tk[r] * NLEN - lane;
    P[8] = nl + PADT * NLEN - lane;    // ins stream

    float C[9][4], N[9][4];
#pragma unroll
    for (int r = 0; r < 9; ++r) {
#pragma unroll
      for (int c = 0; c < 4; ++c) C[r][c] = P[r][c];
    }

    float z[8];
#pragma unroll
    for (int r = 0; r < 8; ++r) z[r] = (float)(base_row + r + 1);  // D[i][0] = i
    float ztop = (float)base_row;                                   // D[8l][0]
    float run = 0.0f;                                               // row-0 prefix
    int s = 0;

#pragma unroll 1
    for (int it = 0; it < 8; ++it) {    // ramp-in, s = 0..63
      dp_iter4<true>(P, C, N, ztop, z, run, s, lane);
      dp_iter4<true>(P, N, C, ztop, z, run, s, lane);
    }
#pragma unroll 1
    for (int it = 0; it < 120; ++it) {  // clean middle, s = 64..1023
      dp_iter4<false>(P, C, N, ztop, z, run, s, lane);
      dp_iter4<false>(P, N, C, ztop, z, run, s, lane);
    }
#pragma unroll 1
    for (int it = 0; it < 8; ++it) {    // ramp-out, s = 1024..1087 (state freezes at col 1024)
      dp_iter4<true>(P, C, N, ztop, z, run, s, lane);
      dp_iter4<true>(P, N, C, ztop, z, run, s, lane);
    }

    // ---- extract D[L][1024] from frozen registers ----
    if (L == 0) {
      if (lane == 0) partial[b] = run;            // D[0][1024] = full ins prefix
    } else {
      const int li = (L - 1) >> 3, qi = (L - 1) & 7;
      if (lane == li) {
        float s01 = (qi & 1) ? z[1] : z[0];
        float s23 = (qi & 1) ? z[3] : z[2];
        float s45 = (qi & 1) ? z[5] : z[4];
        float s67 = (qi & 1) ? z[7] : z[6];
        float s03 = (qi & 2) ? s23 : s01;
        float s47 = (qi & 2) ? s67 : s45;
        partial[b] = (qi & 4) ? s47 : s03;
      }
    }
  }
}

__global__ void reduce_kernel(const float* __restrict__ partial, float* __restrict__ out) {
  if (threadIdx.x == 0) {
    float s = 0.f;
    for (int b2 = 0; b2 < 32; ++b2) s += partial[b2];
    out[0] = s;
  }
}

extern "C" void kernel_launch(void* const* d_in, const int* in_sizes, int n_in,
                              void* d_out, int out_size, void* d_ws, size_t ws_size,
                              hipStream_t stream) {
  const int*   y_true = (const int*)d_in[0];
  const float* y_pred = (const float*)d_in[1];
  float* out = (float*)d_out;
  float* partial = (float*)d_ws;

  const size_t lds_bytes = (size_t)LDS_FLOATS * sizeof(float);   // 133,824 B
  hipFuncSetAttribute((const void*)align_loss_kernel,
                      hipFuncAttributeMaxDynamicSharedMemorySize, (int)lds_bytes);

  hipLaunchKernelGGL(align_loss_kernel, dim3(32), dim3(256), lds_bytes, stream,
                     y_true, y_pred, partial);
  hipLaunchKernelGGL(reduce_kernel, dim3(1), dim3(64), 0, stream, partial, out);
}